// Round 4
// baseline (2613.906 us; speedup 1.0000x reference)
//
#include <hip/hip_runtime.h>
#include <hip/hip_bf16.h>
#include <math.h>

// Problem constants (E83CircularTowerCell): T=2048, B=16, D=1024, n=64, K=3
#define TT 2048
#define BB_ 16
#define DD 1024
#define NN 64
#define KK 3
#define PP 448   // K*2*n + n = 384 + 64

typedef float  v2f  __attribute__((ext_vector_type(2)));
typedef float  f4   __attribute__((ext_vector_type(4)));
typedef float  f32x4 __attribute__((ext_vector_type(4)));
typedef short  bh8  __attribute__((ext_vector_type(8)));

__device__ __forceinline__ float sigmoidf_(float x) {
    return 1.0f / (1.0f + __expf(-x));
}

// LDS-ordering-only barrier: leaves global (vmcnt) loads in flight.
#define LDS_BARRIER() __asm__ volatile("s_waitcnt lgkmcnt(0)\n\ts_barrier" ::: "memory")

// DPP lane-move on the VALU pipe (no LDS/lgkm traffic).
template<int CTRL>
__device__ __forceinline__ float dpp_mov(float v) {
    int r = __builtin_amdgcn_update_dpp(0, __float_as_int(v), CTRL, 0xF, 0xF, true);
    return __int_as_float(r);
}

// Selected-component full 16-lane-row reduction: lane keeps component s
// (s = tc&3); entirely on the VALU pipe (quad_perm + row_ror DPP).
// Proven correct in R1/R3 (absmax 0.0625).
__device__ __forceinline__ float sel16_dpp(const float v[4], int s) {
    const int s0 = s & 1, s1 = (s >> 1) & 1;
    float k0 = s0 ? v[1] : v[0], d0 = s0 ? v[0] : v[1];
    float k1 = s0 ? v[3] : v[2], d1 = s0 ? v[2] : v[3];
    float a0 = k0 + dpp_mov<0xB1>(d0);    // quad_perm [1,0,3,2] : xor1
    float a1 = k1 + dpp_mov<0xB1>(d1);
    float kb = s1 ? a1 : a0, db = s1 ? a0 : a1;
    float r  = kb + dpp_mov<0x4E>(db);    // quad_perm [2,3,0,1] : xor2
    r += dpp_mov<0x124>(r);               // row_ror:4
    r += dpp_mov<0x128>(r);               // row_ror:8
    return r;
}

// ---------------------------------------------------------------------------
// W conversion: Wcat (448 x 1024 fp32, rows 0..383 = W_kv, 384..447 = W_q)
// -> Wsw[kb][n][kk] bf16, kb = k-chunk of 32 (kb = k>>5, kk = k&31).
// ---------------------------------------------------------------------------
__global__ __launch_bounds__(256) void cvt_w_kernel(
    const float* __restrict__ Wkv,
    const float* __restrict__ Wq,
    unsigned short* __restrict__ Wsw)
{
    const int n = blockIdx.x;
    const int tid = threadIdx.x;
    const float* row = (n < 384) ? (Wkv + (size_t)n * DD)
                                 : (Wq  + (size_t)(n - 384) * DD);
    const int idx = tid * 4;           // 4 consecutive k per thread
    const int kb = idx >> 5, kk = idx & 31;
    float4 f = *(const float4*)(row + idx);
    __hip_bfloat162 h0 = __float22bfloat162_rn(make_float2(f.x, f.y));
    __hip_bfloat162 h1 = __float22bfloat162_rn(make_float2(f.z, f.w));
    unsigned u0, u1;
    __builtin_memcpy(&u0, &h0, 4);
    __builtin_memcpy(&u1, &h1, 4);
    ushort4 o = make_ushort4((unsigned short)u0, (unsigned short)(u0 >> 16),
                             (unsigned short)u1, (unsigned short)(u1 >> 16));
    *(ushort4*)&Wsw[((size_t)kb * PP + n) * 32 + kk] = o;
}

// ---------------------------------------------------------------------------
// MFMA projection GEMM: kvq[m][p] = sum_d x[m,d] * Wcat[p][d], m = t*B+b.
// (unchanged)
// ---------------------------------------------------------------------------
__global__ __launch_bounds__(256) void mfma_proj_kernel(
    const float* __restrict__ x,
    const unsigned short* __restrict__ Wsw,
    float* __restrict__ kvq)
{
    const int tid  = threadIdx.x;
    const int w    = tid >> 6;
    const int lane = tid & 63;
    const int ln   = lane & 15;
    const int quad = lane >> 4;
    const int m0   = blockIdx.x * 64;

    f32x4 acc[28];
    #pragma unroll
    for (int t = 0; t < 28; ++t) acc[t] = (f32x4){0.f, 0.f, 0.f, 0.f};

    const float* xrow = x + (size_t)(m0 + 16 * w + ln) * DD + quad * 8;

    for (int kb = 0; kb < 32; ++kb) {
        float4 a0 = *(const float4*)(xrow + kb * 32);
        float4 a1 = *(const float4*)(xrow + kb * 32 + 4);
        __hip_bfloat162 h0 = __float22bfloat162_rn(make_float2(a0.x, a0.y));
        __hip_bfloat162 h1 = __float22bfloat162_rn(make_float2(a0.z, a0.w));
        __hip_bfloat162 h2 = __float22bfloat162_rn(make_float2(a1.x, a1.y));
        __hip_bfloat162 h3 = __float22bfloat162_rn(make_float2(a1.z, a1.w));
        unsigned u0, u1, u2, u3;
        __builtin_memcpy(&u0, &h0, 4); __builtin_memcpy(&u1, &h1, 4);
        __builtin_memcpy(&u2, &h2, 4); __builtin_memcpy(&u3, &h3, 4);
        bh8 a;
        a[0] = (short)u0; a[1] = (short)(u0 >> 16);
        a[2] = (short)u1; a[3] = (short)(u1 >> 16);
        a[4] = (short)u2; a[5] = (short)(u2 >> 16);
        a[6] = (short)u3; a[7] = (short)(u3 >> 16);

        const unsigned short* wp_ = Wsw + (size_t)kb * PP * 32 + quad * 8;
        #pragma unroll
        for (int t = 0; t < 28; ++t) {
            const bh8 bfr = *(const bh8*)(wp_ + (16 * t + ln) * 32);
            acc[t] = __builtin_amdgcn_mfma_f32_16x16x32_bf16(a, bfr, acc[t], 0, 0, 0);
        }
    }

    // Fused k-norm epilogue.
    #pragma unroll
    for (int g = 0; g < 3; ++g) {
        const int t0 = g * 8;
        #pragma unroll
        for (int reg = 0; reg < 4; ++reg) {
            float ss = acc[t0][reg] * acc[t0][reg]
                     + acc[t0 + 1][reg] * acc[t0 + 1][reg]
                     + acc[t0 + 2][reg] * acc[t0 + 2][reg]
                     + acc[t0 + 3][reg] * acc[t0 + 3][reg];
            #pragma unroll
            for (int m = 1; m <= 8; m <<= 1) ss += __shfl_xor(ss, m, 64);
            const float sc = 1.0f / (sqrtf(ss) + 1e-6f);
            #pragma unroll
            for (int t = t0; t < t0 + 4; ++t) acc[t][reg] *= sc;
        }
    }

    float* orow = kvq + (size_t)(m0 + 16 * w + quad * 4) * PP + ln;
    #pragma unroll
    for (int t = 0; t < 28; ++t)
        #pragma unroll
        for (int reg = 0; reg < 4; ++reg)
            orow[(size_t)reg * PP + 16 * t] = acc[t][reg];
}

// ---------------------------------------------------------------------------
// Sequential scan. One block per batch (16 blocks), 12 waves = 768 threads.
// This round: rebalanced 3-phase schedule. bar1 guards ONLY the cs partials
// (short X phase); rp/sp/sel16/sigmoid move between the barriers, running in
// parallel with the combiner's LDS reads. Combine split across 6 waves
// (2 per matrix, 32 cols each, lane-pair q-split + shfl_xor(32)). All LDS
// parity (double-buffer) dims dropped — every array's writer/reader pairs
// are now separated by a barrier in both directions.
// ---------------------------------------------------------------------------
__global__ __launch_bounds__(768) void scan_kernel(
    const float* __restrict__ kvq,
    const float* __restrict__ M_init,
    const float* __restrict__ B_gates,
    float* __restrict__ d_out)
{
    const int b    = blockIdx.x;
    const int tid  = threadIdx.x;
    const int wid  = tid >> 6;        // 0..11
    const int k    = wid >> 2;        // 0..2 : which state matrix
    const int q    = wid & 3;         // row quarter
    const int lane = tid & 63;
    const int tr   = lane >> 4;       // 0..3
    const int tc   = lane & 15;       // 0..15
    const int kp   = (k + 2) % 3;     // gate target (k-1 mod 3)
    const int row0 = 16 * q + 4 * tr;
    const int col0 = 4 * tc;
    const int s3   = tc & 3;
    const int rowS = row0 + s3;       // row this lane finalizes

    __shared__ __align__(16) float cs_lds[3][4][4][64];  // col partials [cls][q][tr][col]
    __shared__ __align__(16) float rg_lds[3][64];        // post-sigmoid row gates
    __shared__ __align__(16) float dl_lds[3][64];        // delta
    __shared__ __align__(16) float cg_lds[3][64];        // post-sigmoid col gates

    v2f M2[4][2];
    #pragma unroll
    for (int i = 0; i < 4; ++i) {
        f4 t = *(const f4*)(M_init + (((size_t)k * BB_ + b) * NN + row0 + i) * NN + col0);
        M2[i][0] = (v2f){t.x, t.y};
        M2[i][1] = (v2f){t.z, t.w};
    }

    const float bias_pub_r = B_gates[kp * NN + rowS];

    // Combiner role: 6 waves (wid 4..9), 2 per matrix cls, 32 cols each.
    // Lane pair (l, l^32) shares col colC; halves sum q={0,1} vs q={2,3}.
    const int  isComb = (wid >= 4) && (wid <= 9);
    const int  cls    = isComb ? ((wid - 4) >> 1) : 0;
    const int  hw     = (wid - 4) & 1;
    const int  colC   = hw * 32 + (lane & 31);
    const int  qsel   = lane >> 5;
    const float cbias = isComb ? B_gates[cls * NN + colC] : 0.f;

    float* outp = d_out;                           // [T][B][n]
    float* Mout = d_out + (size_t)TT * BB_ * NN;   // [K][B][n][n]

    const int o_knc = k * 128 + col0;
    const int o_wpc = kp * 128 + col0;
    const int o_wpr = kp * 128 + row0;
    const int o_v   = k * 128 + 64 + rowS;
    const int o_q   = 384 + col0;

    const float* kvt = kvq + (size_t)b * PP;

    // Parity-indexed register staging (compiler renames under unroll 2).
    f4 sK[2], sC[2], sR[2], sQ[2];
    float sV[2];
    sK[0] = *(const f4*)(kvt + o_knc);
    sC[0] = *(const f4*)(kvt + o_wpc);
    sR[0] = *(const f4*)(kvt + o_wpr);
    sV[0] = kvt[o_v];
    sQ[0] = (f4){0.f, 0.f, 0.f, 0.f};
    if (k == 0) sQ[0] = *(const f4*)(kvt + o_q);
    f4 qp = sQ[0];   // q(t-1); unused at t==0 (store is gated on t>0)

    #pragma unroll 2
    for (int t = 0; t < TT; ++t) {
        const int cur = t & 1, nxt = cur ^ 1;

        // ---- Phase X: prefetch t+1; col-gate partials; cs write; bar1 ----
        const float* kvn = (t + 1 < TT) ? (kvt + (size_t)BB_ * PP) : kvt;
        sK[nxt] = *(const f4*)(kvn + o_knc);
        sC[nxt] = *(const f4*)(kvn + o_wpc);
        sR[nxt] = *(const f4*)(kvn + o_wpr);
        sV[nxt] = kvn[o_v];
        if (k == 0) sQ[nxt] = *(const f4*)(kvn + o_q);

        v2f cp2a, cp2b;
        {
            const v2f w0 = {sR[cur].x, sR[cur].x};
            cp2a = M2[0][0] * w0;
            cp2b = M2[0][1] * w0;
        }
        #pragma unroll
        for (int i = 1; i < 4; ++i) {
            const float w = (i == 1) ? sR[cur].y : (i == 2) ? sR[cur].z : sR[cur].w;
            const v2f wv = {w, w};
            cp2a += M2[i][0] * wv;
            cp2b += M2[i][1] * wv;
        }
        *(f4*)&cs_lds[kp][q][tr][col0] = (f4){cp2a.x, cp2a.y, cp2b.x, cp2b.y};
        LDS_BARRIER();   // barrier 1 — guards cs only

        // ---- Phase Y: combiner reads issue first (latency overlaps VALU) --
        float cv[8];
        if (isComb) {
            #pragma unroll
            for (int qq = 0; qq < 2; ++qq)
                #pragma unroll
                for (int tt = 0; tt < 4; ++tt)
                    cv[qq * 4 + tt] = cs_lds[cls][2 * qsel + qq][tt][colC];
        }

        const v2f kn2a = {sK[cur].x, sK[cur].y}, kn2b = {sK[cur].z, sK[cur].w};
        const v2f wc2a = {sC[cur].x, sC[cur].y}, wc2b = {sC[cur].z, sC[cur].w};

        v2f rp2[4], sp2[4];
        #pragma unroll
        for (int i = 0; i < 4; ++i) {
            rp2[i] = M2[i][0] * kn2a + M2[i][1] * kn2b;
            sp2[i] = M2[i][0] * wc2a + M2[i][1] * wc2b;
        }
        float rp[4], sp[4];
        #pragma unroll
        for (int i = 0; i < 4; ++i) { rp[i] = rp2[i].x + rp2[i].y; sp[i] = sp2[i].x + sp2[i].y; }

        const float rsv = sel16_dpp(sp, s3);
        const float rtv = sel16_dpp(rp, s3);
        const float dv  = sV[cur] - rtv;             // delta for row rowS

        if (tc < 4) {
            rg_lds[kp][rowS] = sigmoidf_(rsv + bias_pub_r);  // final row gate
            dl_lds[k][rowS]  = dv;
        }

        if (isComb) {
            float s = ((cv[0] + cv[1]) + (cv[2] + cv[3]))
                    + ((cv[4] + cv[5]) + (cv[6] + cv[7]));
            s += __shfl_xor(s, 32, 64);              // merge lane-pair halves
            const float g = sigmoidf_(s + cbias);
            if (lane < 32) cg_lds[cls][colC] = g;
        }

        if (k == 0) {
            // Deferred output for t-1 (M2 == M_new(t-1)).
            const v2f qpa = {qp.x, qp.y}, qpb = {qp.z, qp.w};
            float op[4];
            #pragma unroll
            for (int i = 0; i < 4; ++i) {
                v2f o2 = M2[i][0] * qpa + M2[i][1] * qpb;
                op[i] = o2.x + o2.y;
            }
            const float ov = sel16_dpp(op, s3);
            if (t > 0 && tc < 4)
                outp[((size_t)(t - 1) * BB_ + b) * NN + rowS] = ov * sigmoidf_(ov);
        }
        LDS_BARRIER();   // barrier 2 — gates rg/dl/cg to consumers

        // ---- Phase Z: consume final gates, packed update ----
        const f4 rg4 = *(const f4*)&rg_lds[k][row0];
        const f4 dl4 = *(const f4*)&dl_lds[k][row0];
        const f4 cg4 = *(const f4*)&cg_lds[k][col0];
        const v2f cg2a = {cg4.x, cg4.y}, cg2b = {cg4.z, cg4.w};
        #pragma unroll
        for (int i = 0; i < 4; ++i) {
            const float rgi = (i == 0) ? rg4.x : (i == 1) ? rg4.y : (i == 2) ? rg4.z : rg4.w;
            const float ddi = (i == 0) ? dl4.x : (i == 1) ? dl4.y : (i == 2) ? dl4.z : dl4.w;
            const v2f r2 = {rgi, rgi};
            const v2f d2 = {ddi, ddi};
            M2[i][0] = r2 * (M2[i][0] * cg2a) + d2 * kn2a;
            M2[i][1] = r2 * (M2[i][1] * cg2b) + d2 * kn2b;
        }

        qp  = sQ[cur];
        kvt = kvn;
    }

    // Flush deferred output for t = TT-1.
    if (k == 0) {
        const v2f qpa = {qp.x, qp.y}, qpb = {qp.z, qp.w};
        float op[4];
        #pragma unroll
        for (int i = 0; i < 4; ++i) {
            v2f o2 = M2[i][0] * qpa + M2[i][1] * qpb;
            op[i] = o2.x + o2.y;
        }
        const float ov = sel16_dpp(op, s3);
        if (tc < 4)
            outp[((size_t)(TT - 1) * BB_ + b) * NN + rowS] = ov * sigmoidf_(ov);
    }

    // Final state write-out.
    #pragma unroll
    for (int i = 0; i < 4; ++i) {
        f4 v = (f4){M2[i][0].x, M2[i][0].y, M2[i][1].x, M2[i][1].y};
        *(f4*)&Mout[(((size_t)k * BB_ + b) * NN + row0 + i) * NN + col0] = v;
    }
}

extern "C" void kernel_launch(void* const* d_in, const int* in_sizes, int n_in,
                              void* d_out, int out_size, void* d_ws, size_t ws_size,
                              hipStream_t stream) {
    const float* x       = (const float*)d_in[0];
    const float* M_init  = (const float*)d_in[1];
    const float* W_kv    = (const float*)d_in[2];
    const float* W_q     = (const float*)d_in[3];
    const float* B_gates = (const float*)d_in[4];
    float* out = (float*)d_out;

    float* kvq = (float*)d_ws;                       // 56 MB
    const size_t kvq_bytes = (size_t)TT * BB_ * PP * 4;
    unsigned short* Wsw = (unsigned short*)((char*)d_ws + kvq_bytes);  // 896 KB

    cvt_w_kernel<<<PP, 256, 0, stream>>>(W_kv, W_q, Wsw);
    mfma_proj_kernel<<<TT * BB_ / 64, 256, 0, stream>>>(x, Wsw, kvq);
    scan_kernel<<<BB_, 768, 0, stream>>>(kvq, M_init, B_gates, out);
}

// Round 5
// 2497.274 us; speedup vs baseline: 1.0467x; 1.0467x over previous
//
#include <hip/hip_runtime.h>
#include <hip/hip_bf16.h>
#include <math.h>

// Problem constants (E83CircularTowerCell): T=2048, B=16, D=1024, n=64, K=3
#define TT 2048
#define BB_ 16
#define DD 1024
#define NN 64
#define KK 3
#define PP 448   // K*2*n + n = 384 + 64

typedef float  v2f  __attribute__((ext_vector_type(2)));
typedef float  f4   __attribute__((ext_vector_type(4)));
typedef float  f32x4 __attribute__((ext_vector_type(4)));
typedef short  bh8  __attribute__((ext_vector_type(8)));

__device__ __forceinline__ float sigmoidf_(float x) {
    return 1.0f / (1.0f + __expf(-x));
}

// LDS-ordering-only barrier: leaves global (vmcnt) loads in flight.
#define LDS_BARRIER() __asm__ volatile("s_waitcnt lgkmcnt(0)\n\ts_barrier" ::: "memory")

// DPP lane-move on the VALU pipe (no LDS/lgkm traffic).
template<int CTRL>
__device__ __forceinline__ float dpp_mov(float v) {
    int r = __builtin_amdgcn_update_dpp(0, __float_as_int(v), CTRL, 0xF, 0xF, true);
    return __int_as_float(r);
}

// Selected-component full 16-lane-row reduction: lane keeps component s
// (s = tc&3); entirely on the VALU pipe (quad_perm + row_ror DPP).
// Proven correct in R1/R3 (absmax 0.0625).
__device__ __forceinline__ float sel16_dpp(const float v[4], int s) {
    const int s0 = s & 1, s1 = (s >> 1) & 1;
    float k0 = s0 ? v[1] : v[0], d0 = s0 ? v[0] : v[1];
    float k1 = s0 ? v[3] : v[2], d1 = s0 ? v[2] : v[3];
    float a0 = k0 + dpp_mov<0xB1>(d0);    // quad_perm [1,0,3,2] : xor1
    float a1 = k1 + dpp_mov<0xB1>(d1);
    float kb = s1 ? a1 : a0, db = s1 ? a0 : a1;
    float r  = kb + dpp_mov<0x4E>(db);    // quad_perm [2,3,0,1] : xor2
    r += dpp_mov<0x124>(r);               // row_ror:4
    r += dpp_mov<0x128>(r);               // row_ror:8
    return r;
}

// ---------------------------------------------------------------------------
// W conversion: Wcat (448 x 1024 fp32, rows 0..383 = W_kv, 384..447 = W_q)
// -> Wsw[kb][n][kk] bf16, kb = k-chunk of 32 (kb = k>>5, kk = k&31).
// ---------------------------------------------------------------------------
__global__ __launch_bounds__(256) void cvt_w_kernel(
    const float* __restrict__ Wkv,
    const float* __restrict__ Wq,
    unsigned short* __restrict__ Wsw)
{
    const int n = blockIdx.x;
    const int tid = threadIdx.x;
    const float* row = (n < 384) ? (Wkv + (size_t)n * DD)
                                 : (Wq  + (size_t)(n - 384) * DD);
    const int idx = tid * 4;           // 4 consecutive k per thread
    const int kb = idx >> 5, kk = idx & 31;
    float4 f = *(const float4*)(row + idx);
    __hip_bfloat162 h0 = __float22bfloat162_rn(make_float2(f.x, f.y));
    __hip_bfloat162 h1 = __float22bfloat162_rn(make_float2(f.z, f.w));
    unsigned u0, u1;
    __builtin_memcpy(&u0, &h0, 4);
    __builtin_memcpy(&u1, &h1, 4);
    ushort4 o = make_ushort4((unsigned short)u0, (unsigned short)(u0 >> 16),
                             (unsigned short)u1, (unsigned short)(u1 >> 16));
    *(ushort4*)&Wsw[((size_t)kb * PP + n) * 32 + kk] = o;
}

// ---------------------------------------------------------------------------
// MFMA projection GEMM: kvq[m][p] = sum_d x[m,d] * Wcat[p][d], m = t*B+b.
// (unchanged)
// ---------------------------------------------------------------------------
__global__ __launch_bounds__(256) void mfma_proj_kernel(
    const float* __restrict__ x,
    const unsigned short* __restrict__ Wsw,
    float* __restrict__ kvq)
{
    const int tid  = threadIdx.x;
    const int w    = tid >> 6;
    const int lane = tid & 63;
    const int ln   = lane & 15;
    const int quad = lane >> 4;
    const int m0   = blockIdx.x * 64;

    f32x4 acc[28];
    #pragma unroll
    for (int t = 0; t < 28; ++t) acc[t] = (f32x4){0.f, 0.f, 0.f, 0.f};

    const float* xrow = x + (size_t)(m0 + 16 * w + ln) * DD + quad * 8;

    for (int kb = 0; kb < 32; ++kb) {
        float4 a0 = *(const float4*)(xrow + kb * 32);
        float4 a1 = *(const float4*)(xrow + kb * 32 + 4);
        __hip_bfloat162 h0 = __float22bfloat162_rn(make_float2(a0.x, a0.y));
        __hip_bfloat162 h1 = __float22bfloat162_rn(make_float2(a0.z, a0.w));
        __hip_bfloat162 h2 = __float22bfloat162_rn(make_float2(a1.x, a1.y));
        __hip_bfloat162 h3 = __float22bfloat162_rn(make_float2(a1.z, a1.w));
        unsigned u0, u1, u2, u3;
        __builtin_memcpy(&u0, &h0, 4); __builtin_memcpy(&u1, &h1, 4);
        __builtin_memcpy(&u2, &h2, 4); __builtin_memcpy(&u3, &h3, 4);
        bh8 a;
        a[0] = (short)u0; a[1] = (short)(u0 >> 16);
        a[2] = (short)u1; a[3] = (short)(u1 >> 16);
        a[4] = (short)u2; a[5] = (short)(u2 >> 16);
        a[6] = (short)u3; a[7] = (short)(u3 >> 16);

        const unsigned short* wp_ = Wsw + (size_t)kb * PP * 32 + quad * 8;
        #pragma unroll
        for (int t = 0; t < 28; ++t) {
            const bh8 bfr = *(const bh8*)(wp_ + (16 * t + ln) * 32);
            acc[t] = __builtin_amdgcn_mfma_f32_16x16x32_bf16(a, bfr, acc[t], 0, 0, 0);
        }
    }

    // Fused k-norm epilogue.
    #pragma unroll
    for (int g = 0; g < 3; ++g) {
        const int t0 = g * 8;
        #pragma unroll
        for (int reg = 0; reg < 4; ++reg) {
            float ss = acc[t0][reg] * acc[t0][reg]
                     + acc[t0 + 1][reg] * acc[t0 + 1][reg]
                     + acc[t0 + 2][reg] * acc[t0 + 2][reg]
                     + acc[t0 + 3][reg] * acc[t0 + 3][reg];
            #pragma unroll
            for (int m = 1; m <= 8; m <<= 1) ss += __shfl_xor(ss, m, 64);
            const float sc = 1.0f / (sqrtf(ss) + 1e-6f);
            #pragma unroll
            for (int t = t0; t < t0 + 4; ++t) acc[t][reg] *= sc;
        }
    }

    float* orow = kvq + (size_t)(m0 + 16 * w + quad * 4) * PP + ln;
    #pragma unroll
    for (int t = 0; t < 28; ++t)
        #pragma unroll
        for (int reg = 0; reg < 4; ++reg)
            orow[(size_t)reg * PP + 16 * t] = acc[t][reg];
}

// ---------------------------------------------------------------------------
// Sequential scan. One block per batch (16 blocks), 12 waves = 768 threads.
// R5: back to the PROVEN R3 schedule (long pre-bar1 all-wave phase -> bar1 ->
// balanced bubble {k=1 combine, k=0 deferred output} -> bar2 -> update), with:
//  - no LDS parity dims (barrier-separated in both directions; audited),
//  - dl_lds eliminated: dv register-carried, Z uses quad_perm broadcasts,
//  - Z issues the cg read first and computes cg-independent work under it.
// ---------------------------------------------------------------------------
__global__ __launch_bounds__(768) void scan_kernel(
    const float* __restrict__ kvq,
    const float* __restrict__ M_init,
    const float* __restrict__ B_gates,
    float* __restrict__ d_out)
{
    const int b    = blockIdx.x;
    const int tid  = threadIdx.x;
    const int wid  = tid >> 6;        // 0..11
    const int k    = wid >> 2;        // 0..2 : which state matrix
    const int q    = wid & 3;         // row quarter
    const int lane = tid & 63;
    const int tr   = lane >> 4;       // 0..3
    const int tc   = lane & 15;       // 0..15
    const int kp   = (k + 2) % 3;     // gate target (k-1 mod 3)
    const int row0 = 16 * q + 4 * tr;
    const int col0 = 4 * tc;
    const int s3   = tc & 3;
    const int rowS = row0 + s3;       // row this lane finalizes

    __shared__ __align__(16) float cs_lds[3][4][4][64];  // col partials [cls][q][tr][col]
    __shared__ __align__(16) float rg_lds[3][64];        // post-sigmoid row gates
    __shared__ __align__(16) float cg_lds[3][64];        // post-sigmoid col gates

    v2f M2[4][2];
    #pragma unroll
    for (int i = 0; i < 4; ++i) {
        f4 t = *(const f4*)(M_init + (((size_t)k * BB_ + b) * NN + row0 + i) * NN + col0);
        M2[i][0] = (v2f){t.x, t.y};
        M2[i][1] = (v2f){t.z, t.w};
    }

    const float bias_pub_r = B_gates[kp * NN + rowS];
    // Combiner role: waves wid 4..6 (k=1) finalize col gates for class wid-4.
    const int  isComb = (wid >= 4) && (wid < 7);
    const int  cls    = isComb ? (wid - 4) : 0;
    const float cbias = isComb ? B_gates[cls * NN + lane] : 0.f;

    float* outp = d_out;                           // [T][B][n]
    float* Mout = d_out + (size_t)TT * BB_ * NN;   // [K][B][n][n]

    const int o_knc = k * 128 + col0;
    const int o_wpc = kp * 128 + col0;
    const int o_wpr = kp * 128 + row0;
    const int o_v   = k * 128 + 64 + rowS;
    const int o_q   = 384 + col0;

    const float* kvt = kvq + (size_t)b * PP;

    // Parity-indexed register staging (compiler renames under unroll 2).
    f4 sK[2], sC[2], sR[2], sQ[2];
    float sV[2];
    sK[0] = *(const f4*)(kvt + o_knc);
    sC[0] = *(const f4*)(kvt + o_wpc);
    sR[0] = *(const f4*)(kvt + o_wpr);
    sV[0] = kvt[o_v];
    sQ[0] = (f4){0.f, 0.f, 0.f, 0.f};
    if (k == 0) sQ[0] = *(const f4*)(kvt + o_q);
    f4 qp = sQ[0];   // q(t-1); unused at t==0 (store is gated on t>0)

    #pragma unroll 2
    for (int t = 0; t < TT; ++t) {
        const int cur = t & 1, nxt = cur ^ 1;

        // ---- Phase A (pre-bar1, all waves symmetric) ----
        // Prefetch t+1 (stays in flight across both lgkm-only barriers).
        const float* kvn = (t + 1 < TT) ? (kvt + (size_t)BB_ * PP) : kvt;
        sK[nxt] = *(const f4*)(kvn + o_knc);
        sC[nxt] = *(const f4*)(kvn + o_wpc);
        sR[nxt] = *(const f4*)(kvn + o_wpr);
        sV[nxt] = kvn[o_v];
        if (k == 0) sQ[nxt] = *(const f4*)(kvn + o_q);

        const v2f kn2a = {sK[cur].x, sK[cur].y}, kn2b = {sK[cur].z, sK[cur].w};
        const v2f wc2a = {sC[cur].x, sC[cur].y}, wc2b = {sC[cur].z, sC[cur].w};

        // Col-gate partials -> one b128 LDS write (no cross-lane reduce).
        v2f cp2a, cp2b;
        {
            const v2f w0 = {sR[cur].x, sR[cur].x};
            cp2a = M2[0][0] * w0;
            cp2b = M2[0][1] * w0;
        }
        #pragma unroll
        for (int i = 1; i < 4; ++i) {
            const float w = (i == 1) ? sR[cur].y : (i == 2) ? sR[cur].z : sR[cur].w;
            const v2f wv = {w, w};
            cp2a += M2[i][0] * wv;
            cp2b += M2[i][1] * wv;
        }
        *(f4*)&cs_lds[kp][q][tr][col0] = (f4){cp2a.x, cp2a.y, cp2b.x, cp2b.y};

        // Row-dot partials.
        v2f rp2[4], sp2[4];
        #pragma unroll
        for (int i = 0; i < 4; ++i) {
            rp2[i] = M2[i][0] * kn2a + M2[i][1] * kn2b;
            sp2[i] = M2[i][0] * wc2a + M2[i][1] * wc2b;
        }
        float rp[4], sp[4];
        #pragma unroll
        for (int i = 0; i < 4; ++i) { rp[i] = rp2[i].x + rp2[i].y; sp[i] = sp2[i].x + sp2[i].y; }

        const float rsv = sel16_dpp(sp, s3);
        const float rtv = sel16_dpp(rp, s3);
        const float dv  = sV[cur] - rtv;   // delta for row 4tr+(tc&3); REGISTER-carried to Z

        if (tc < 4)
            rg_lds[kp][rowS] = sigmoidf_(rsv + bias_pub_r);  // final row gate
        LDS_BARRIER();   // barrier 1

        // ---- Bubble: k=1 waves combine col gates; k=0 waves do the deferred
        //      t-1 output; all waves read their row gates (latency hidden). --
        const f4 rg4 = *(const f4*)&rg_lds[k][row0];
        if (isComb) {
            float s0 = cs_lds[cls][0][0][lane] + cs_lds[cls][0][1][lane]
                     + cs_lds[cls][0][2][lane] + cs_lds[cls][0][3][lane];
            float s1 = cs_lds[cls][1][0][lane] + cs_lds[cls][1][1][lane]
                     + cs_lds[cls][1][2][lane] + cs_lds[cls][1][3][lane];
            float s2 = cs_lds[cls][2][0][lane] + cs_lds[cls][2][1][lane]
                     + cs_lds[cls][2][2][lane] + cs_lds[cls][2][3][lane];
            float s3_ = cs_lds[cls][3][0][lane] + cs_lds[cls][3][1][lane]
                     + cs_lds[cls][3][2][lane] + cs_lds[cls][3][3][lane];
            cg_lds[cls][lane] = sigmoidf_((s0 + s1) + (s2 + s3_) + cbias);
        }
        if (k == 0) {
            // Deferred output for t-1 (M2 == M_new(t-1)).
            const v2f qpa = {qp.x, qp.y}, qpb = {qp.z, qp.w};
            float op[4];
            #pragma unroll
            for (int i = 0; i < 4; ++i) {
                v2f o2 = M2[i][0] * qpa + M2[i][1] * qpb;
                op[i] = o2.x + o2.y;
            }
            const float ov = sel16_dpp(op, s3);
            if (t > 0 && tc < 4)
                outp[((size_t)(t - 1) * BB_ + b) * NN + rowS] = ov * sigmoidf_(ov);
        }
        LDS_BARRIER();   // barrier 2

        // ---- Phase Z: issue cg read, overlap cg-independent work under it --
        const f4 cg4 = *(const f4*)&cg_lds[k][col0];

        // Per-row delta via quad_perm broadcast of register-carried dv
        // (replaces dl_lds write+read): dd[i] = dv of lane with tc&3 == i.
        float dd0 = dpp_mov<0x00>(dv);   // quad_perm [0,0,0,0]
        float dd1 = dpp_mov<0x55>(dv);   // quad_perm [1,1,1,1]
        float dd2 = dpp_mov<0xAA>(dv);   // quad_perm [2,2,2,2]
        float dd3 = dpp_mov<0xFF>(dv);   // quad_perm [3,3,3,3]

        // cg-independent products first (hide the cg ds_read latency).
        v2f ta[4], tb[4];
        {
            const v2f d0v = {dd0, dd0}, d1v = {dd1, dd1}, d2v = {dd2, dd2}, d3v = {dd3, dd3};
            ta[0] = d0v * kn2a; tb[0] = d0v * kn2b;
            ta[1] = d1v * kn2a; tb[1] = d1v * kn2b;
            ta[2] = d2v * kn2a; tb[2] = d2v * kn2b;
            ta[3] = d3v * kn2a; tb[3] = d3v * kn2b;
        }

        const v2f cg2a = {cg4.x, cg4.y}, cg2b = {cg4.z, cg4.w};
        #pragma unroll
        for (int i = 0; i < 4; ++i) {
            const float rgi = (i == 0) ? rg4.x : (i == 1) ? rg4.y : (i == 2) ? rg4.z : rg4.w;
            const v2f r2 = {rgi, rgi};
            M2[i][0] = r2 * (M2[i][0] * cg2a) + ta[i];
            M2[i][1] = r2 * (M2[i][1] * cg2b) + tb[i];
        }

        qp  = sQ[cur];
        kvt = kvn;
    }

    // Flush deferred output for t = TT-1.
    if (k == 0) {
        const v2f qpa = {qp.x, qp.y}, qpb = {qp.z, qp.w};
        float op[4];
        #pragma unroll
        for (int i = 0; i < 4; ++i) {
            v2f o2 = M2[i][0] * qpa + M2[i][1] * qpb;
            op[i] = o2.x + o2.y;
        }
        const float ov = sel16_dpp(op, s3);
        if (tc < 4)
            outp[((size_t)(TT - 1) * BB_ + b) * NN + rowS] = ov * sigmoidf_(ov);
    }

    // Final state write-out.
    #pragma unroll
    for (int i = 0; i < 4; ++i) {
        f4 v = (f4){M2[i][0].x, M2[i][0].y, M2[i][1].x, M2[i][1].y};
        *(f4*)&Mout[(((size_t)k * BB_ + b) * NN + row0 + i) * NN + col0] = v;
    }
}

extern "C" void kernel_launch(void* const* d_in, const int* in_sizes, int n_in,
                              void* d_out, int out_size, void* d_ws, size_t ws_size,
                              hipStream_t stream) {
    const float* x       = (const float*)d_in[0];
    const float* M_init  = (const float*)d_in[1];
    const float* W_kv    = (const float*)d_in[2];
    const float* W_q     = (const float*)d_in[3];
    const float* B_gates = (const float*)d_in[4];
    float* out = (float*)d_out;

    float* kvq = (float*)d_ws;                       // 56 MB
    const size_t kvq_bytes = (size_t)TT * BB_ * PP * 4;
    unsigned short* Wsw = (unsigned short*)((char*)d_ws + kvq_bytes);  // 896 KB

    cvt_w_kernel<<<PP, 256, 0, stream>>>(W_kv, W_q, Wsw);
    mfma_proj_kernel<<<TT * BB_ / 64, 256, 0, stream>>>(x, Wsw, kvq);
    scan_kernel<<<BB_, 768, 0, stream>>>(kvq, M_init, B_gates, out);
}

// Round 6
// 2079.345 us; speedup vs baseline: 1.2571x; 1.2010x over previous
//
#include <hip/hip_runtime.h>
#include <hip/hip_bf16.h>
#include <math.h>

// Problem constants (E83CircularTowerCell): T=2048, B=16, D=1024, n=64, K=3
#define TT 2048
#define BB_ 16
#define DD 1024
#define NN 64
#define KK 3
#define PP 448   // K*2*n + n = 384 + 64

typedef float  v2f  __attribute__((ext_vector_type(2)));
typedef float  f4   __attribute__((ext_vector_type(4)));
typedef float  f32x4 __attribute__((ext_vector_type(4)));
typedef short  bh8  __attribute__((ext_vector_type(8)));

__device__ __forceinline__ float sigmoidf_(float x) {
    return 1.0f / (1.0f + __expf(-x));
}

// LDS-ordering-only barrier: leaves global (vmcnt) loads in flight.
#define LDS_BARRIER() __asm__ volatile("s_waitcnt lgkmcnt(0)\n\ts_barrier" ::: "memory")

// DPP lane-move on the VALU pipe (no LDS/lgkm traffic).
template<int CTRL>
__device__ __forceinline__ float dpp_mov(float v) {
    int r = __builtin_amdgcn_update_dpp(0, __float_as_int(v), CTRL, 0xF, 0xF, true);
    return __int_as_float(r);
}

// Selected-component full 16-lane-row reduction: lane keeps component s
// (s = tc&3); entirely on the VALU pipe (quad_perm + row_ror DPP).
// Proven correct in R1/R3 (absmax 0.0625).
__device__ __forceinline__ float sel16_dpp(const float v[4], int s) {
    const int s0 = s & 1, s1 = (s >> 1) & 1;
    float k0 = s0 ? v[1] : v[0], d0 = s0 ? v[0] : v[1];
    float k1 = s0 ? v[3] : v[2], d1 = s0 ? v[2] : v[3];
    float a0 = k0 + dpp_mov<0xB1>(d0);    // quad_perm [1,0,3,2] : xor1
    float a1 = k1 + dpp_mov<0xB1>(d1);
    float kb = s1 ? a1 : a0, db = s1 ? a0 : a1;
    float r  = kb + dpp_mov<0x4E>(db);    // quad_perm [2,3,0,1] : xor2
    r += dpp_mov<0x124>(r);               // row_ror:4
    r += dpp_mov<0x128>(r);               // row_ror:8
    return r;
}

// ---------------------------------------------------------------------------
// W conversion: Wcat (448 x 1024 fp32, rows 0..383 = W_kv, 384..447 = W_q)
// -> Wsw[kb][n][kk] bf16, kb = k-chunk of 32 (kb = k>>5, kk = k&31).
// ---------------------------------------------------------------------------
__global__ __launch_bounds__(256) void cvt_w_kernel(
    const float* __restrict__ Wkv,
    const float* __restrict__ Wq,
    unsigned short* __restrict__ Wsw)
{
    const int n = blockIdx.x;
    const int tid = threadIdx.x;
    const float* row = (n < 384) ? (Wkv + (size_t)n * DD)
                                 : (Wq  + (size_t)(n - 384) * DD);
    const int idx = tid * 4;           // 4 consecutive k per thread
    const int kb = idx >> 5, kk = idx & 31;
    float4 f = *(const float4*)(row + idx);
    __hip_bfloat162 h0 = __float22bfloat162_rn(make_float2(f.x, f.y));
    __hip_bfloat162 h1 = __float22bfloat162_rn(make_float2(f.z, f.w));
    unsigned u0, u1;
    __builtin_memcpy(&u0, &h0, 4);
    __builtin_memcpy(&u1, &h1, 4);
    ushort4 o = make_ushort4((unsigned short)u0, (unsigned short)(u0 >> 16),
                             (unsigned short)u1, (unsigned short)(u1 >> 16));
    *(ushort4*)&Wsw[((size_t)kb * PP + n) * 32 + kk] = o;
}

// ---------------------------------------------------------------------------
// MFMA projection GEMM: kvq[m][p] = sum_d x[m,d] * Wcat[p][d], m = t*B+b.
// (unchanged)
// ---------------------------------------------------------------------------
__global__ __launch_bounds__(256) void mfma_proj_kernel(
    const float* __restrict__ x,
    const unsigned short* __restrict__ Wsw,
    float* __restrict__ kvq)
{
    const int tid  = threadIdx.x;
    const int w    = tid >> 6;
    const int lane = tid & 63;
    const int ln   = lane & 15;
    const int quad = lane >> 4;
    const int m0   = blockIdx.x * 64;

    f32x4 acc[28];
    #pragma unroll
    for (int t = 0; t < 28; ++t) acc[t] = (f32x4){0.f, 0.f, 0.f, 0.f};

    const float* xrow = x + (size_t)(m0 + 16 * w + ln) * DD + quad * 8;

    for (int kb = 0; kb < 32; ++kb) {
        float4 a0 = *(const float4*)(xrow + kb * 32);
        float4 a1 = *(const float4*)(xrow + kb * 32 + 4);
        __hip_bfloat162 h0 = __float22bfloat162_rn(make_float2(a0.x, a0.y));
        __hip_bfloat162 h1 = __float22bfloat162_rn(make_float2(a0.z, a0.w));
        __hip_bfloat162 h2 = __float22bfloat162_rn(make_float2(a1.x, a1.y));
        __hip_bfloat162 h3 = __float22bfloat162_rn(make_float2(a1.z, a1.w));
        unsigned u0, u1, u2, u3;
        __builtin_memcpy(&u0, &h0, 4); __builtin_memcpy(&u1, &h1, 4);
        __builtin_memcpy(&u2, &h2, 4); __builtin_memcpy(&u3, &h3, 4);
        bh8 a;
        a[0] = (short)u0; a[1] = (short)(u0 >> 16);
        a[2] = (short)u1; a[3] = (short)(u1 >> 16);
        a[4] = (short)u2; a[5] = (short)(u2 >> 16);
        a[6] = (short)u3; a[7] = (short)(u3 >> 16);

        const unsigned short* wp_ = Wsw + (size_t)kb * PP * 32 + quad * 8;
        #pragma unroll
        for (int t = 0; t < 28; ++t) {
            const bh8 bfr = *(const bh8*)(wp_ + (16 * t + ln) * 32);
            acc[t] = __builtin_amdgcn_mfma_f32_16x16x32_bf16(a, bfr, acc[t], 0, 0, 0);
        }
    }

    // Fused k-norm epilogue.
    #pragma unroll
    for (int g = 0; g < 3; ++g) {
        const int t0 = g * 8;
        #pragma unroll
        for (int reg = 0; reg < 4; ++reg) {
            float ss = acc[t0][reg] * acc[t0][reg]
                     + acc[t0 + 1][reg] * acc[t0 + 1][reg]
                     + acc[t0 + 2][reg] * acc[t0 + 2][reg]
                     + acc[t0 + 3][reg] * acc[t0 + 3][reg];
            #pragma unroll
            for (int m = 1; m <= 8; m <<= 1) ss += __shfl_xor(ss, m, 64);
            const float sc = 1.0f / (sqrtf(ss) + 1e-6f);
            #pragma unroll
            for (int t = t0; t < t0 + 4; ++t) acc[t][reg] *= sc;
        }
    }

    float* orow = kvq + (size_t)(m0 + 16 * w + quad * 4) * PP + ln;
    #pragma unroll
    for (int t = 0; t < 28; ++t)
        #pragma unroll
        for (int reg = 0; reg < 4; ++reg)
            orow[(size_t)reg * PP + 16 * t] = acc[t][reg];
}

// ---------------------------------------------------------------------------
// Sequential scan. One block per batch (16 blocks), now 16 waves = 1024 thr:
// 12 M-waves carry EXACTLY R3's per-tile arithmetic; 3 dedicated service
// waves (wid 12..14) do ONLY the col-gate combine; wid 15 idles at barriers.
// Schedule: A-pre(cp+cs) -> bar1 -> {M: rp/sp/sel16/rg/dl  ||  svc: combine}
// -> bar2 -> Z(read gates; k0 deferred output under read latency; update).
// The R3 bubble is deleted from the serial chain. All LDS keeps parity dims.
// ---------------------------------------------------------------------------
__global__ __launch_bounds__(1024) void scan_kernel(
    const float* __restrict__ kvq,
    const float* __restrict__ M_init,
    const float* __restrict__ B_gates,
    float* __restrict__ d_out)
{
    const int b    = blockIdx.x;
    const int tid  = threadIdx.x;
    const int wid  = tid >> 6;        // 0..15
    const int lane = tid & 63;

    __shared__ __align__(16) float cs_lds[2][3][4][4][64];  // col partials [pb][cls][q][tr][col]
    __shared__ __align__(16) float rg_lds[2][3][64];        // post-sigmoid row gates
    __shared__ __align__(16) float dl_lds[2][3][64];        // delta
    __shared__ __align__(16) float cg_lds[2][3][64];        // post-sigmoid col gates

    if (wid >= 12) {
        // ================= service waves =================
        const int  act = (wid < 15);
        const int  cls = act ? (wid - 12) : 0;
        const float cbias = act ? B_gates[cls * NN + lane] : 0.f;
        #pragma unroll 2
        for (int t = 0; t < TT; ++t) {
            const int pb = t & 1;
            LDS_BARRIER();   // bar1 — cs ready
            if (act) {
                float s0 = (cs_lds[pb][cls][0][0][lane] + cs_lds[pb][cls][0][1][lane])
                         + (cs_lds[pb][cls][0][2][lane] + cs_lds[pb][cls][0][3][lane]);
                float s1 = (cs_lds[pb][cls][1][0][lane] + cs_lds[pb][cls][1][1][lane])
                         + (cs_lds[pb][cls][1][2][lane] + cs_lds[pb][cls][1][3][lane]);
                float s2 = (cs_lds[pb][cls][2][0][lane] + cs_lds[pb][cls][2][1][lane])
                         + (cs_lds[pb][cls][2][2][lane] + cs_lds[pb][cls][2][3][lane]);
                float s3 = (cs_lds[pb][cls][3][0][lane] + cs_lds[pb][cls][3][1][lane])
                         + (cs_lds[pb][cls][3][2][lane] + cs_lds[pb][cls][3][3][lane]);
                cg_lds[pb][cls][lane] = sigmoidf_((s0 + s1) + (s2 + s3) + cbias);
            }
            LDS_BARRIER();   // bar2 — cg published
        }
        return;
    }

    // ================= M-waves (wid 0..11) =================
    const int k    = wid >> 2;        // 0..2 : which state matrix
    const int q    = wid & 3;         // row quarter
    const int tr   = lane >> 4;       // 0..3
    const int tc   = lane & 15;       // 0..15
    const int kp   = (k + 2) % 3;     // gate target (k-1 mod 3)
    const int row0 = 16 * q + 4 * tr;
    const int col0 = 4 * tc;
    const int s3   = tc & 3;
    const int rowS = row0 + s3;       // row this lane finalizes

    v2f M2[4][2];
    #pragma unroll
    for (int i = 0; i < 4; ++i) {
        f4 t = *(const f4*)(M_init + (((size_t)k * BB_ + b) * NN + row0 + i) * NN + col0);
        M2[i][0] = (v2f){t.x, t.y};
        M2[i][1] = (v2f){t.z, t.w};
    }

    const float bias_pub_r = B_gates[kp * NN + rowS];

    float* outp = d_out;                           // [T][B][n]
    float* Mout = d_out + (size_t)TT * BB_ * NN;   // [K][B][n][n]

    const int o_knc = k * 128 + col0;
    const int o_wpc = kp * 128 + col0;
    const int o_wpr = kp * 128 + row0;
    const int o_v   = k * 128 + 64 + rowS;
    const int o_q   = 384 + col0;

    const float* kvt = kvq + (size_t)b * PP;

    // Parity-indexed register staging (compiler renames under unroll 2).
    f4 sK[2], sC[2], sR[2], sQ[2];
    float sV[2];
    sK[0] = *(const f4*)(kvt + o_knc);
    sC[0] = *(const f4*)(kvt + o_wpc);
    sR[0] = *(const f4*)(kvt + o_wpr);
    sV[0] = kvt[o_v];
    sQ[0] = (f4){0.f, 0.f, 0.f, 0.f};
    if (k == 0) sQ[0] = *(const f4*)(kvt + o_q);
    f4 qp = sQ[0];   // q(t-1); unused at t==0 (store is gated on t>0)

    #pragma unroll 2
    for (int t = 0; t < TT; ++t) {
        const int pb  = t & 1;
        const int cur = t & 1, nxt = cur ^ 1;

        // ---- Phase A-pre: prefetch t+1; col-gate partials; cs write ----
        const float* kvn = (t + 1 < TT) ? (kvt + (size_t)BB_ * PP) : kvt;
        sK[nxt] = *(const f4*)(kvn + o_knc);
        sC[nxt] = *(const f4*)(kvn + o_wpc);
        sR[nxt] = *(const f4*)(kvn + o_wpr);
        sV[nxt] = kvn[o_v];
        if (k == 0) sQ[nxt] = *(const f4*)(kvn + o_q);

        v2f cp2a, cp2b;
        {
            const v2f w0 = {sR[cur].x, sR[cur].x};
            cp2a = M2[0][0] * w0;
            cp2b = M2[0][1] * w0;
        }
        #pragma unroll
        for (int i = 1; i < 4; ++i) {
            const float w = (i == 1) ? sR[cur].y : (i == 2) ? sR[cur].z : sR[cur].w;
            const v2f wv = {w, w};
            cp2a += M2[i][0] * wv;
            cp2b += M2[i][1] * wv;
        }
        *(f4*)&cs_lds[pb][kp][q][tr][col0] = (f4){cp2a.x, cp2a.y, cp2b.x, cp2b.y};
        LDS_BARRIER();   // barrier 1 — guards cs only

        // ---- Window: row-dot partials + reduces (svc combines in parallel) -
        const v2f kn2a = {sK[cur].x, sK[cur].y}, kn2b = {sK[cur].z, sK[cur].w};
        const v2f wc2a = {sC[cur].x, sC[cur].y}, wc2b = {sC[cur].z, sC[cur].w};

        v2f rp2[4], sp2[4];
        #pragma unroll
        for (int i = 0; i < 4; ++i) {
            rp2[i] = M2[i][0] * kn2a + M2[i][1] * kn2b;
            sp2[i] = M2[i][0] * wc2a + M2[i][1] * wc2b;
        }
        float rp[4], sp[4];
        #pragma unroll
        for (int i = 0; i < 4; ++i) { rp[i] = rp2[i].x + rp2[i].y; sp[i] = sp2[i].x + sp2[i].y; }

        const float rsv = sel16_dpp(sp, s3);
        const float rtv = sel16_dpp(rp, s3);
        const float dv  = sV[cur] - rtv;             // delta for row rowS

        if (tc < 4) {
            rg_lds[pb][kp][rowS] = sigmoidf_(rsv + bias_pub_r);  // final row gate
            dl_lds[pb][k][rowS]  = dv;
        }
        LDS_BARRIER();   // barrier 2 — rg/dl/cg all published

        // ---- Phase Z: read gates; k0 output under read latency; update ----
        const f4 rg4 = *(const f4*)&rg_lds[pb][k][row0];
        const f4 dl4 = *(const f4*)&dl_lds[pb][k][row0];
        const f4 cg4 = *(const f4*)&cg_lds[pb][k][col0];

        if (k == 0) {
            // Deferred output for t-1 (M2 is still M_new(t-1) here).
            const v2f qpa = {qp.x, qp.y}, qpb = {qp.z, qp.w};
            float op[4];
            #pragma unroll
            for (int i = 0; i < 4; ++i) {
                v2f o2 = M2[i][0] * qpa + M2[i][1] * qpb;
                op[i] = o2.x + o2.y;
            }
            const float ov = sel16_dpp(op, s3);
            if (t > 0 && tc < 4)
                outp[((size_t)(t - 1) * BB_ + b) * NN + rowS] = ov * sigmoidf_(ov);
        }

        const v2f cg2a = {cg4.x, cg4.y}, cg2b = {cg4.z, cg4.w};
        #pragma unroll
        for (int i = 0; i < 4; ++i) {
            const float rgi = (i == 0) ? rg4.x : (i == 1) ? rg4.y : (i == 2) ? rg4.z : rg4.w;
            const float ddi = (i == 0) ? dl4.x : (i == 1) ? dl4.y : (i == 2) ? dl4.z : dl4.w;
            const v2f r2 = {rgi, rgi};
            const v2f d2 = {ddi, ddi};
            M2[i][0] = r2 * (M2[i][0] * cg2a) + d2 * kn2a;
            M2[i][1] = r2 * (M2[i][1] * cg2b) + d2 * kn2b;
        }

        qp  = sQ[cur];
        kvt = kvn;
    }

    // Flush deferred output for t = TT-1.
    if (k == 0) {
        const v2f qpa = {qp.x, qp.y}, qpb = {qp.z, qp.w};
        float op[4];
        #pragma unroll
        for (int i = 0; i < 4; ++i) {
            v2f o2 = M2[i][0] * qpa + M2[i][1] * qpb;
            op[i] = o2.x + o2.y;
        }
        const float ov = sel16_dpp(op, s3);
        if (tc < 4)
            outp[((size_t)(TT - 1) * BB_ + b) * NN + rowS] = ov * sigmoidf_(ov);
    }

    // Final state write-out.
    #pragma unroll
    for (int i = 0; i < 4; ++i) {
        f4 v = (f4){M2[i][0].x, M2[i][0].y, M2[i][1].x, M2[i][1].y};
        *(f4*)&Mout[(((size_t)k * BB_ + b) * NN + row0 + i) * NN + col0] = v;
    }
}

extern "C" void kernel_launch(void* const* d_in, const int* in_sizes, int n_in,
                              void* d_out, int out_size, void* d_ws, size_t ws_size,
                              hipStream_t stream) {
    const float* x       = (const float*)d_in[0];
    const float* M_init  = (const float*)d_in[1];
    const float* W_kv    = (const float*)d_in[2];
    const float* W_q     = (const float*)d_in[3];
    const float* B_gates = (const float*)d_in[4];
    float* out = (float*)d_out;

    float* kvq = (float*)d_ws;                       // 56 MB
    const size_t kvq_bytes = (size_t)TT * BB_ * PP * 4;
    unsigned short* Wsw = (unsigned short*)((char*)d_ws + kvq_bytes);  // 896 KB

    cvt_w_kernel<<<PP, 256, 0, stream>>>(W_kv, W_q, Wsw);
    mfma_proj_kernel<<<TT * BB_ / 64, 256, 0, stream>>>(x, Wsw, kvq);
    scan_kernel<<<BB_, 1024, 0, stream>>>(kvq, M_init, B_gates, out);
}